// Round 6
// baseline (134.628 us; speedup 1.0000x reference)
//
#include <hip/hip_runtime.h>

// CNN encoder as implicit-im2col GEMM:
//   A(M=32*2040, K=1024) x Wp(K=1024, N=256), Wp[fd][k] = filt[fd]*W_k[fd][k]
//   out = relu(A*Wp + b_k)
// Round 6: 4 waves of 64x128 (LDS traffic 375 B/MFMA), BK=32 double-buffered
// sB (stage c+1 issued before compute c -> barrier drain hidden), A slab
// staged in 4 d-slices overlapped with first 3 chunks, chunk-order rotation
// decorrelates the two co-resident blocks' L2 bursts.

#define L_SZ   2048
#define NWIN   2040   // L - F (reference uses L - F)
#define BM     128
#define MT     16

typedef __attribute__((ext_vector_type(8))) short bf16x8;
typedef __attribute__((ext_vector_type(4))) short bf16x4;
typedef __attribute__((ext_vector_type(4))) float f32x4;

static __device__ __forceinline__ short f2bf(float f) {
    union { float f; unsigned u; } v; v.f = f;
    unsigned r = v.u + 0x7FFFu + ((v.u >> 16) & 1u);
    return (short)(r >> 16);
}

static __device__ __forceinline__ void gload_lds16(const short* g, short* l) {
    __builtin_amdgcn_global_load_lds(
        (const __attribute__((address_space(1))) unsigned int*)g,
        (__attribute__((address_space(3))) unsigned int*)l, 16, 0, 0);
}

// ---- prep: wp2 = 32 regions (BK=32 chunks) of 16KB, 1024 slots of 16B each.
// Slot w in region R: np = w>>2 (n 0..255), pos = w&3; holds
// Wp[np][R*32 + (pos^((np>>1)&3))*8 .. +8], Wp[k][n] = Wk[k][n]*filt[k].
// XOR-swizzle baked in: staging stays lane-linear, b-frag ds_read_b128 2-way.
__global__ __launch_bounds__(256) void prep_w_kernel(
    const float* __restrict__ Wk, const float* __restrict__ filt,
    short* __restrict__ wp2)
{
    int g   = blockIdx.x * 256 + threadIdx.x;  // 32768 slots
    int R   = g >> 10;                         // chunk 0..31
    int w   = g & 1023;
    int np  = w >> 2;                          // n 0..255
    int pos = w & 3;
    int cs  = pos ^ ((np >> 1) & 3);
    int kb  = R * 32 + cs * 8;
    bf16x8 o;
    #pragma unroll
    for (int jj = 0; jj < 8; ++jj)
        o[jj] = f2bf(Wk[(size_t)(kb + jj) * 256 + np] * filt[kb + jj]);
    *reinterpret_cast<bf16x8*>(&wp2[(size_t)g * 8]) = o;
}

__global__ __launch_bounds__(256, 2) void cnn_enc_kernel(
    const float* __restrict__ ub, const short* __restrict__ wp2,
    const float* __restrict__ bk, float* __restrict__ out)
{
    // A slab: 135 rows x 128 d bf16, stride 136
    __shared__ short sA[135 * 136];    // 36720 B
    // B: 2 buffers of 256 n x 32 k bf16, lane-linear staged, swizzle baked
    __shared__ short sB[2 * 8192];     // 32768 B  (total 69488 -> 2 blk/CU)

    const int tid   = threadIdx.x;
    const int bid   = blockIdx.x;
    const int mt    = bid & 15;          // M-tile
    const int batch = bid >> 4;          // 0..31
    const int rot   = (bid >> 8) << 4;   // co-resident blocks: start chunk 0/16
    const int l0    = mt * BM;

    const int lane = tid & 63;
    const int wave = tid >> 6;     // 0..3
    const int wm   = wave >> 1;    // 0..1  (64-row sub-tile)
    const int wn   = wave & 1;     // 0..1  (128-col sub-tile)
    const int t16  = lane & 15;
    const int quad = lane >> 4;

    // ---- A d-slice staging: slice s = cols [s*32, s*32+32), all 135 rows
    auto stageA = [&](int s) {
        for (int idx = tid; idx < 135 * 8; idx += 256) {
            int r  = idx >> 3;
            int c4 = idx & 7;                       // float4 within slice
            int rg = l0 + r; if (rg > L_SZ - 1) rg = L_SZ - 1;
            const float4 v = *reinterpret_cast<const float4*>(
                ub + (((size_t)batch * L_SZ + rg) << 7) + s * 32 + c4 * 4);
            bf16x4 o;
            o.x = f2bf(v.x); o.y = f2bf(v.y); o.z = f2bf(v.z); o.w = f2bf(v.w);
            *reinterpret_cast<bf16x4*>(&sA[r * 136 + s * 32 + c4 * 4]) = o;
        }
    };
    // ---- B chunk staging: 16 KB lane-linear into buf
    auto stageB = [&](int c, int buf) {
        const short* wpb = wp2 + (size_t)c * 8192;
        #pragma unroll
        for (int r = 0; r < 4; ++r) {
            int ubase = r * 256 + wave * 64;        // 16B-unit, wave-uniform
            gload_lds16(wpb + (ubase + lane) * 8, &sB[buf * 8192 + ubase * 8]);
        }
    };

    f32x4 acc[4][8];
    #pragma unroll
    for (int i = 0; i < 4; ++i)
        #pragma unroll
        for (int j = 0; j < 8; ++j)
            acc[i][j] = (f32x4){0.f, 0.f, 0.f, 0.f};

    int aoff[4];
    #pragma unroll
    for (int i = 0; i < 4; ++i)
        aoff[i] = (wm * 64 + i * 16 + t16) * 136 + quad * 8;
    int bpos[8];
    #pragma unroll
    for (int j = 0; j < 8; ++j) {
        int np = wn * 128 + j * 16 + t16;
        bpos[j] = np * 32 + (quad ^ ((np >> 1) & 3)) * 8;
    }

    stageA(0);
    stageB(rot, 0);
    __syncthreads();

    #pragma unroll 1
    for (int c = 0; c < 32; ++c) {
        if (c < 3)  stageA(c + 1);                       // overlap A prologue
        if (c < 31) stageB((c + 1 + rot) & 31, (c + 1) & 1);
        const int ce = (c + rot) & 31;                   // rotation: ce&3 == c&3
        const int f  = ce >> 2, ds = ce & 3;
        const int bb = (c & 1) * 8192;
        bf16x8 a[4], b[8];
        #pragma unroll
        for (int i = 0; i < 4; ++i)
            a[i] = *reinterpret_cast<const bf16x8*>(
                &sA[aoff[i] + f * 136 + ds * 32]);
        #pragma unroll
        for (int j = 0; j < 8; ++j)
            b[j] = *reinterpret_cast<const bf16x8*>(&sB[bb + bpos[j]]);
        #pragma unroll
        for (int i = 0; i < 4; ++i)
            #pragma unroll
            for (int j = 0; j < 8; ++j)
                acc[i][j] = __builtin_amdgcn_mfma_f32_16x16x32_bf16(
                    a[i], b[j], acc[i][j], 0, 0, 0);
        __syncthreads();   // drains stage(c+1) AFTER compute; frees buf for c+2
    }

    // ---- epilogue: bias + relu; C/D: col=lane&15, row=quad*4+reg
    #pragma unroll
    for (int j = 0; j < 8; ++j) {
        int n_glob = wn * 128 + j * 16 + t16;
        float bias = bk[n_glob];
        #pragma unroll
        for (int i = 0; i < 4; ++i) {
            #pragma unroll
            for (int r = 0; r < 4; ++r) {
                int l = l0 + wm * 64 + i * 16 + quad * 4 + r;
                if (l < NWIN) {
                    float v = acc[i][j][r] + bias;
                    out[((size_t)batch * NWIN + l) * 256 + n_glob] =
                        v > 0.f ? v : 0.f;
                }
            }
        }
    }
}

extern "C" void kernel_launch(void* const* d_in, const int* in_sizes, int n_in,
                              void* d_out, int out_size, void* d_ws, size_t ws_size,
                              hipStream_t stream) {
    const float* ub   = (const float*)d_in[0];  // (32,2048,128) fp32
    const float* filt = (const float*)d_in[1];  // (8,128) fp32
    const float* Wk   = (const float*)d_in[2];  // (1024,256) fp32
    const float* bk   = (const float*)d_in[3];  // (256,) fp32
    float* out = (float*)d_out;                 // (32,2040,256) fp32
    short* wp2 = (short*)d_ws;                  // 512 KB re-tiled Wp^T

    hipLaunchKernelGGL(prep_w_kernel, dim3(128), dim3(256), 0, stream,
                       Wk, filt, wp2);
    hipLaunchKernelGGL(cnn_enc_kernel, dim3(32 * MT), dim3(256), 0, stream,
                       ub, wp2, bk, out);
}

// Round 7
// 126.153 us; speedup vs baseline: 1.0672x; 1.0672x over previous
//
#include <hip/hip_runtime.h>

// CNN encoder as implicit-im2col GEMM:
//   A(M=32*2040, K=1024) x Wp(K=1024, N=256), Wp[fd][k] = filt[fd]*W_k[fd][k]
//   out = relu(A*Wp + b_k)
// Round 7: R5 structure (512 thr, 8 waves of 64x64, 2 blk/CU, 16 waves/CU)
// + BK=32 double-buffered sB (stage c+1 issued a full iter before its drain)
// + A slab staged in 4 d-quarters overlapped with iters 0..2.

#define L_SZ   2048
#define NWIN   2040   // L - F (reference uses L - F)
#define BM     128
#define MT     16

typedef __attribute__((ext_vector_type(8))) short bf16x8;
typedef __attribute__((ext_vector_type(4))) short bf16x4;
typedef __attribute__((ext_vector_type(4))) float f32x4;

static __device__ __forceinline__ short f2bf(float f) {
    union { float f; unsigned u; } v; v.f = f;
    unsigned r = v.u + 0x7FFFu + ((v.u >> 16) & 1u);
    return (short)(r >> 16);
}

static __device__ __forceinline__ void gload_lds16(const short* g, short* l) {
    __builtin_amdgcn_global_load_lds(
        (const __attribute__((address_space(1))) unsigned int*)g,
        (__attribute__((address_space(3))) unsigned int*)l, 16, 0, 0);
}

// ---- prep: wp2 = 32 regions (BK=32 chunks) of 16KB, 1024 slots of 16B each.
// Slot w in region R: np = w>>2 (n 0..255), pos = w&3; holds
// Wp[np][R*32 + (pos^((np>>1)&3))*8 .. +8], Wp[k][n] = Wk[k][n]*filt[k].
// XOR swizzle baked in: staging stays lane-linear, b-frag ds_read_b128
// spreads uniformly over all 32 banks.
__global__ __launch_bounds__(256) void prep_w_kernel(
    const float* __restrict__ Wk, const float* __restrict__ filt,
    short* __restrict__ wp2)
{
    int g   = blockIdx.x * 256 + threadIdx.x;  // 32768 slots
    int R   = g >> 10;                         // chunk 0..31
    int w   = g & 1023;
    int np  = w >> 2;                          // n 0..255
    int pos = w & 3;
    int cs  = pos ^ ((np >> 1) & 3);
    int kb  = R * 32 + cs * 8;
    bf16x8 o;
    #pragma unroll
    for (int jj = 0; jj < 8; ++jj)
        o[jj] = f2bf(Wk[(size_t)(kb + jj) * 256 + np] * filt[kb + jj]);
    *reinterpret_cast<bf16x8*>(&wp2[(size_t)g * 8]) = o;
}

__global__ __launch_bounds__(512, 4) void cnn_enc_kernel(
    const float* __restrict__ ub, const short* __restrict__ wp2,
    const float* __restrict__ bk, float* __restrict__ out)
{
    // A slab: 135 rows x 128 d bf16, stride 136 (a-frag reads 2-way = free)
    __shared__ short sA[135 * 136];    // 36720 B
    // B: 2 buffers of 256 n x 32 k bf16, lane-linear staged, swizzle baked
    __shared__ short sB[2 * 8192];     // 32768 B  (total 69488 -> 2 blk/CU)

    const int tid   = threadIdx.x;
    const int bid   = blockIdx.x;
    const int mt    = bid & 15;          // M-tile
    const int batch = bid >> 4;          // 0..31
    const int l0    = mt * BM;

    const int lane = tid & 63;
    const int wave = tid >> 6;     // 0..7
    const int wm   = wave >> 2;    // 0..1  (64-row sub-tile)
    const int wn   = wave & 3;     // 0..3  (64-col sub-tile)
    const int t16  = lane & 15;
    const int quad = lane >> 4;

    // ---- A d-quarter staging: quarter q = cols [q*32, q*32+32), 135 rows
    auto stageA = [&](int q) {
        for (int idx = tid; idx < 135 * 8; idx += 512) {
            int r  = idx >> 3;
            int c4 = idx & 7;
            int rg = l0 + r; if (rg > L_SZ - 1) rg = L_SZ - 1;
            const float4 v = *reinterpret_cast<const float4*>(
                ub + (((size_t)batch * L_SZ + rg) << 7) + q * 32 + c4 * 4);
            bf16x4 o;
            o.x = f2bf(v.x); o.y = f2bf(v.y); o.z = f2bf(v.z); o.w = f2bf(v.w);
            *reinterpret_cast<bf16x4*>(&sA[r * 136 + q * 32 + c4 * 4]) = o;
        }
    };
    // ---- B chunk staging: 16 KB lane-linear into buffer `buf`
    auto stageB = [&](int c, int buf) {
        const short* wpb = wp2 + (size_t)c * 8192;
        #pragma unroll
        for (int r = 0; r < 2; ++r) {
            int ubase = r * 512 + wave * 64;        // 16B-unit, wave-uniform
            gload_lds16(wpb + (ubase + lane) * 8, &sB[buf * 8192 + ubase * 8]);
        }
    };

    f32x4 acc[4][4];
    #pragma unroll
    for (int i = 0; i < 4; ++i)
        #pragma unroll
        for (int j = 0; j < 4; ++j)
            acc[i][j] = (f32x4){0.f, 0.f, 0.f, 0.f};

    int aoff[4];
    #pragma unroll
    for (int i = 0; i < 4; ++i)
        aoff[i] = (wm * 64 + i * 16 + t16) * 136 + quad * 8;
    int bpos[4];
    #pragma unroll
    for (int j = 0; j < 4; ++j) {
        int np = wn * 64 + j * 16 + t16;            // n 0..255
        bpos[j] = np * 32 + (quad ^ ((np >> 1) & 3)) * 8;
    }

    stageA(0);          // d-quarter 0, needed at iter 0
    stageB(0, 0);
    __syncthreads();

    #pragma unroll 1
    for (int c = 0; c < 32; ++c) {
        if (c < 3)  stageA(c + 1);                  // quarter q needed iter q
        if (c < 31) stageB(c + 1, (c + 1) & 1);     // drained at THIS barrier
        const int f  = c >> 2, ds = c & 3;
        const int bb = (c & 1) * 8192;
        bf16x8 a[4], b[4];
        #pragma unroll
        for (int i = 0; i < 4; ++i)
            a[i] = *reinterpret_cast<const bf16x8*>(
                &sA[aoff[i] + f * 136 + ds * 32]);
        #pragma unroll
        for (int j = 0; j < 4; ++j)
            b[j] = *reinterpret_cast<const bf16x8*>(&sB[bb + bpos[j]]);
        #pragma unroll
        for (int i = 0; i < 4; ++i)
            #pragma unroll
            for (int j = 0; j < 4; ++j)
                acc[i][j] = __builtin_amdgcn_mfma_f32_16x16x32_bf16(
                    a[i], b[j], acc[i][j], 0, 0, 0);
        __syncthreads();   // frees buf(c) for stage(c+2); drains stage(c+1)
    }

    // ---- epilogue: bias + relu; C/D: col=lane&15, row=quad*4+reg
    #pragma unroll
    for (int j = 0; j < 4; ++j) {
        int n_glob = wn * 64 + j * 16 + t16;
        float bias = bk[n_glob];
        #pragma unroll
        for (int i = 0; i < 4; ++i) {
            #pragma unroll
            for (int r = 0; r < 4; ++r) {
                int l = l0 + wm * 64 + i * 16 + quad * 4 + r;
                if (l < NWIN) {
                    float v = acc[i][j][r] + bias;
                    out[((size_t)batch * NWIN + l) * 256 + n_glob] =
                        v > 0.f ? v : 0.f;
                }
            }
        }
    }
}

extern "C" void kernel_launch(void* const* d_in, const int* in_sizes, int n_in,
                              void* d_out, int out_size, void* d_ws, size_t ws_size,
                              hipStream_t stream) {
    const float* ub   = (const float*)d_in[0];  // (32,2048,128) fp32
    const float* filt = (const float*)d_in[1];  // (8,128) fp32
    const float* Wk   = (const float*)d_in[2];  // (1024,256) fp32
    const float* bk   = (const float*)d_in[3];  // (256,) fp32
    float* out = (float*)d_out;                 // (32,2040,256) fp32
    short* wp2 = (short*)d_ws;                  // 512 KB re-tiled Wp^T

    hipLaunchKernelGGL(prep_w_kernel, dim3(128), dim3(256), 0, stream,
                       Wk, filt, wp2);
    hipLaunchKernelGGL(cnn_enc_kernel, dim3(32 * MT), dim3(512), 0, stream,
                       ub, wp2, bk, out);
}

// Round 8
// 124.403 us; speedup vs baseline: 1.0822x; 1.0141x over previous
//
#include <hip/hip_runtime.h>

// CNN encoder as implicit-im2col GEMM:
//   A(M=32*2040, K=1024) x Wp(K=1024, N=256), Wp[fd][k] = filt[fd]*W_k[fd][k]
//   out = relu(A*Wp + b_k)
// Round 8: R7 structure (512 thr, 8 waves of 64x64, 2 blk/CU, dbuf BK=32 sB,
// A staged in d-quarters) but with v_mfma_f32_32x32x16_bf16: 15% faster pipe
// (2382 vs 2075 TF), half the MFMA instruction count, full-line C stores.

#define L_SZ   2048
#define NWIN   2040   // L - F (reference uses L - F)
#define BM     128
#define MT     16

typedef __attribute__((ext_vector_type(8)))  short bf16x8;
typedef __attribute__((ext_vector_type(4)))  short bf16x4;
typedef __attribute__((ext_vector_type(16))) float f32x16;

static __device__ __forceinline__ short f2bf(float f) {
    union { float f; unsigned u; } v; v.f = f;
    unsigned r = v.u + 0x7FFFu + ((v.u >> 16) & 1u);
    return (short)(r >> 16);
}

static __device__ __forceinline__ void gload_lds16(const short* g, short* l) {
    __builtin_amdgcn_global_load_lds(
        (const __attribute__((address_space(1))) unsigned int*)g,
        (__attribute__((address_space(3))) unsigned int*)l, 16, 0, 0);
}

// ---- prep: wp2 = 32 regions (BK=32 chunks) of 16KB, 1024 slots of 16B each.
// Slot w in region R: np = w>>2 (n 0..255), pos = w&3; holds
// Wp[np][R*32 + (pos^((np>>1)&3))*8 .. +8], Wp[k][n] = Wk[k][n]*filt[k].
// XOR swizzle baked in: staging lane-linear, b-frag ds_read_b128 balanced.
__global__ __launch_bounds__(256) void prep_w_kernel(
    const float* __restrict__ Wk, const float* __restrict__ filt,
    short* __restrict__ wp2)
{
    int g   = blockIdx.x * 256 + threadIdx.x;  // 32768 slots
    int R   = g >> 10;                         // chunk 0..31
    int w   = g & 1023;
    int np  = w >> 2;                          // n 0..255
    int pos = w & 3;
    int cs  = pos ^ ((np >> 1) & 3);
    int kb  = R * 32 + cs * 8;
    bf16x8 o;
    #pragma unroll
    for (int jj = 0; jj < 8; ++jj)
        o[jj] = f2bf(Wk[(size_t)(kb + jj) * 256 + np] * filt[kb + jj]);
    *reinterpret_cast<bf16x8*>(&wp2[(size_t)g * 8]) = o;
}

__global__ __launch_bounds__(512, 4) void cnn_enc_kernel(
    const float* __restrict__ ub, const short* __restrict__ wp2,
    const float* __restrict__ bk, float* __restrict__ out)
{
    // A slab: 135 rows x 128 d bf16, stride 136 (32-row a-frag b128 reads
    // land 8 accesses/bank = balanced)
    __shared__ short sA[135 * 136];    // 36720 B
    // B: 2 buffers of 256 n x 32 k bf16, lane-linear staged, swizzle baked
    __shared__ short sB[2 * 8192];     // 32768 B  (total 69488 -> 2 blk/CU)

    const int tid   = threadIdx.x;
    const int bid   = blockIdx.x;
    const int mt    = bid & 15;          // M-tile
    const int batch = bid >> 4;          // 0..31
    const int l0    = mt * BM;

    const int lane = tid & 63;
    const int wave = tid >> 6;     // 0..7
    const int wm   = wave >> 2;    // 0..1  (64-row sub-tile)
    const int wn   = wave & 3;     // 0..3  (64-col sub-tile)
    const int l32  = lane & 31;
    const int half = lane >> 5;    // 0..1

    // ---- A d-quarter staging: quarter q = cols [q*32, q*32+32), 135 rows
    auto stageA = [&](int q) {
        for (int idx = tid; idx < 135 * 8; idx += 512) {
            int r  = idx >> 3;
            int c4 = idx & 7;
            int rg = l0 + r; if (rg > L_SZ - 1) rg = L_SZ - 1;
            const float4 v = *reinterpret_cast<const float4*>(
                ub + (((size_t)batch * L_SZ + rg) << 7) + q * 32 + c4 * 4);
            bf16x4 o;
            o.x = f2bf(v.x); o.y = f2bf(v.y); o.z = f2bf(v.z); o.w = f2bf(v.w);
            *reinterpret_cast<bf16x4*>(&sA[r * 136 + q * 32 + c4 * 4]) = o;
        }
    };
    // ---- B chunk staging: 16 KB lane-linear into buffer `buf`
    auto stageB = [&](int c, int buf) {
        const short* wpb = wp2 + (size_t)c * 8192;
        #pragma unroll
        for (int r = 0; r < 2; ++r) {
            int ubase = r * 512 + wave * 64;        // 16B-unit, wave-uniform
            gload_lds16(wpb + (ubase + lane) * 8, &sB[buf * 8192 + ubase * 8]);
        }
    };

    f32x16 acc[2][2];
    #pragma unroll
    for (int i = 0; i < 2; ++i)
        #pragma unroll
        for (int j = 0; j < 2; ++j)
            acc[i][j] = (f32x16){0.f,0.f,0.f,0.f,0.f,0.f,0.f,0.f,
                                 0.f,0.f,0.f,0.f,0.f,0.f,0.f,0.f};

    // a-frag base offsets (shorts): row = wm*64 + i*32 + l32 (+f later),
    // d = ds*32 + ks*16 + half*8
    int aoff[2];
    #pragma unroll
    for (int i = 0; i < 2; ++i)
        aoff[i] = (wm * 64 + i * 32 + l32) * 136 + half * 8;
    // b-frag offsets (shorts): np = wn*64 + j*32 + l32; chunk8 c8 = ks*2+half,
    // pos = c8 ^ ((np>>1)&3); addr = np*32 + pos*8
    int bnp[2], bxor[2];
    #pragma unroll
    for (int j = 0; j < 2; ++j) {
        int np = wn * 64 + j * 32 + l32;
        bnp[j]  = np * 32;
        bxor[j] = (np >> 1) & 3;
    }

    stageA(0);          // d-quarter 0, needed at iter 0
    stageB(0, 0);
    __syncthreads();

    #pragma unroll 1
    for (int c = 0; c < 32; ++c) {
        if (c < 3)  stageA(c + 1);                  // quarter q needed iter q
        if (c < 31) stageB(c + 1, (c + 1) & 1);     // drained at THIS barrier
        const int f  = c >> 2, ds = c & 3;
        const int bb = (c & 1) * 8192;
        bf16x8 a[2][2], b[2][2];                    // [ks][i/j]
        #pragma unroll
        for (int ks = 0; ks < 2; ++ks) {
            #pragma unroll
            for (int i = 0; i < 2; ++i)
                a[ks][i] = *reinterpret_cast<const bf16x8*>(
                    &sA[aoff[i] + f * 136 + ds * 32 + ks * 16]);
            #pragma unroll
            for (int j = 0; j < 2; ++j) {
                int c8 = ks * 2 + half;
                b[ks][j] = *reinterpret_cast<const bf16x8*>(
                    &sB[bb + bnp[j] + (c8 ^ bxor[j]) * 8]);
            }
        }
        #pragma unroll
        for (int ks = 0; ks < 2; ++ks)
            #pragma unroll
            for (int i = 0; i < 2; ++i)
                #pragma unroll
                for (int j = 0; j < 2; ++j)
                    acc[i][j] = __builtin_amdgcn_mfma_f32_32x32x16_bf16(
                        a[ks][i], b[ks][j], acc[i][j], 0, 0, 0);
        __syncthreads();   // frees buf(c) for stage(c+2); drains stage(c+1)
    }

    // ---- epilogue: bias + relu
    // C/D 32x32: col = lane&31, row = (reg&3) + 8*(reg>>2) + 4*(lane>>5)
    #pragma unroll
    for (int j = 0; j < 2; ++j) {
        int n_glob = wn * 64 + j * 32 + l32;
        float bias = bk[n_glob];
        #pragma unroll
        for (int i = 0; i < 2; ++i) {
            #pragma unroll
            for (int r = 0; r < 16; ++r) {
                int row = (r & 3) + 8 * (r >> 2) + 4 * half;
                int l = l0 + wm * 64 + i * 32 + row;
                if (l < NWIN) {
                    float v = acc[i][j][r] + bias;
                    out[((size_t)batch * NWIN + l) * 256 + n_glob] =
                        v > 0.f ? v : 0.f;
                }
            }
        }
    }
}

extern "C" void kernel_launch(void* const* d_in, const int* in_sizes, int n_in,
                              void* d_out, int out_size, void* d_ws, size_t ws_size,
                              hipStream_t stream) {
    const float* ub   = (const float*)d_in[0];  // (32,2048,128) fp32
    const float* filt = (const float*)d_in[1];  // (8,128) fp32
    const float* Wk   = (const float*)d_in[2];  // (1024,256) fp32
    const float* bk   = (const float*)d_in[3];  // (256,) fp32
    float* out = (float*)d_out;                 // (32,2040,256) fp32
    short* wp2 = (short*)d_ws;                  // 512 KB re-tiled Wp^T

    hipLaunchKernelGGL(prep_w_kernel, dim3(128), dim3(256), 0, stream,
                       Wk, filt, wp2);
    hipLaunchKernelGGL(cnn_enc_kernel, dim3(32 * MT), dim3(512), 0, stream,
                       ub, wp2, bk, out);
}